// Round 1
// baseline (1630.188 us; speedup 1.0000x reference)
//
#include <hip/hip_runtime.h>
#include <hip/hip_bf16.h>

// MoE FFN: B=4 T=2048 D=1024 F=4096 E=8 top-2, fp32 in/out.
// Strategy: fp32 router -> expert buckets -> bf16 MFMA grouped GEMMs
// (stage A: x@w1, x@w3 fused SwiGLU -> h; stage B: h@w2 -> pout -> combine).
// R2: XOR-swizzled LDS granule placement kills the 4-8 way bank conflicts.
// R3: (a) double-buffered prefetch K-loop (T3-minimum 2-phase): issue next
//     K-step's global_load_lds BEFORE current step's ds_read+MFMA, ONE
//     vmcnt(0)+barrier per step instead of a serial drain between two barriers.
//     k_ffn1 was 437 TF / MfmaUtil 18% with the fully-serialized loop.
//     (b) k_ffn2 epilogue: atomicAdd(out) replaced by per-pair fp32 rows
//     (pout, aliased onto w1t which is dead after ffn1) + k_combine gather.

#define NTOK 8192
#define DMODEL 1024
#define FDIM 4096
#define NEXP 8

typedef __attribute__((ext_vector_type(8))) short s8v;   // 8 x bf16 (4 VGPR)
typedef __attribute__((ext_vector_type(4))) float f4v;   // MFMA accumulator

__device__ __forceinline__ int imin(int a, int b){ return a < b ? a : b; }

// fp32 -> bf16 round-to-nearest-even
__device__ __forceinline__ unsigned short f2b(float f){
  union { float f; unsigned u; } v; v.f = f;
  unsigned r = v.u + 0x7fffu + ((v.u >> 16) & 1u);
  return (unsigned short)(r >> 16);
}

__device__ __forceinline__ f4v mfma16(s8v a, s8v b, f4v c){
  return __builtin_amdgcn_mfma_f32_16x16x32_bf16(a, b, c, 0, 0, 0);
}

// async global->LDS, 16B/lane; LDS dest = wave-uniform base + lane*16
#define GLDS16(gp, lp) __builtin_amdgcn_global_load_lds(                      \
    (const __attribute__((address_space(1))) void*)(gp),                      \
    (__attribute__((address_space(3))) void*)(lp), 16, 0, 0)

// LDS swizzle: source 16B-granule g of row r lives at LDS position g ^ ((r>>1)&3).
// Staging lane L (row r=L>>2, LDS pos L&3) therefore FETCHES source granule
// (L&3)^((L>>3)&3); fragment reads at row lm, granule quad use LDS position
// quad^((lm>>1)&3). Row-base offsets are multiples of 16 so they drop out.

// ---------------- fp32 -> bf16 elementwise (x) ----------------
__global__ void k_cvt(const float4* __restrict__ in, ushort4* __restrict__ out, int n4){
  int i = blockIdx.x * blockDim.x + threadIdx.x;
  int st = gridDim.x * blockDim.x;
  for(; i < n4; i += st){
    float4 v = in[i];
    ushort4 o;
    o.x = f2b(v.x); o.y = f2b(v.y); o.z = f2b(v.z); o.w = f2b(v.w);
    out[i] = o;
  }
}

// ---------------- fp32 [e][R][C] -> bf16 [e][C][R] transpose ----------------
__global__ void k_tr(const float* __restrict__ in, unsigned short* __restrict__ out,
                     int R, int C){
  __shared__ float tile[32][33];
  const float* src = in + (size_t)blockIdx.z * R * C;
  unsigned short* dst = out + (size_t)blockIdx.z * R * C;
  int bx = blockIdx.x * 32, by = blockIdx.y * 32;
  int tx = threadIdx.x & 31, ty = threadIdx.x >> 5;
  #pragma unroll
  for(int i = 0; i < 32; i += 8)
    tile[ty + i][tx] = src[(size_t)(by + ty + i) * C + bx + tx];
  __syncthreads();
  #pragma unroll
  for(int i = 0; i < 32; i += 8)
    dst[(size_t)(bx + ty + i) * R + by + tx] = f2b(tile[tx][ty + i]);
}

// ---------------- router: fp32 logits -> softmax -> top2 -> renorm ----------------
__global__ void k_router(const float* __restrict__ x, const float* __restrict__ gw,
                         int* __restrict__ route_e, float* __restrict__ route_w,
                         int* __restrict__ counts){
  int lane = threadIdx.x & 63;
  int t = blockIdx.x * 4 + (threadIdx.x >> 6);   // one wave per token
  const float* xr = x + (size_t)t * DMODEL;
  float acc[NEXP];
  #pragma unroll
  for(int e = 0; e < NEXP; e++) acc[e] = 0.f;
  for(int d = lane; d < DMODEL; d += 64){
    float xv = xr[d];
    const float* g = gw + d * NEXP;
    #pragma unroll
    for(int e = 0; e < NEXP; e++) acc[e] += xv * g[e];
  }
  #pragma unroll
  for(int off = 32; off > 0; off >>= 1){
    #pragma unroll
    for(int e = 0; e < NEXP; e++) acc[e] += __shfl_down(acc[e], off, 64);
  }
  if(lane == 0){
    float mx = acc[0];
    #pragma unroll
    for(int e = 1; e < NEXP; e++) mx = fmaxf(mx, acc[e]);
    float p[NEXP];
    #pragma unroll
    for(int e = 0; e < NEXP; e++) p[e] = expf(acc[e] - mx);
    int i0 = 0;
    #pragma unroll
    for(int e = 1; e < NEXP; e++) if(p[e] > p[i0]) i0 = e;     // first-max (jax tie rule)
    int i1 = (i0 == 0) ? 1 : 0;
    #pragma unroll
    for(int e = 0; e < NEXP; e++) if(e != i0 && p[e] > p[i1]) i1 = e;
    float inv = 1.f / (p[i0] + p[i1]);           // softmax denom cancels in ratio
    route_e[2*t]   = i0; route_e[2*t+1] = i1;
    route_w[2*t]   = p[i0] * inv;
    route_w[2*t+1] = p[i1] * inv;
    atomicAdd(&counts[i0], 1); atomicAdd(&counts[i1], 1);
  }
}

__global__ void k_scan(const int* __restrict__ counts, int* __restrict__ offsets,
                       int* __restrict__ cursor){
  if(threadIdx.x == 0){
    int o = 0;
    for(int e = 0; e < NEXP; e++){ offsets[e] = o; o += counts[e]; cursor[e] = 0; }
    offsets[NEXP] = o;
  }
}

__global__ void k_fill(const int* __restrict__ route_e, const float* __restrict__ route_w,
                       const int* __restrict__ offsets, int* __restrict__ cursor,
                       int* __restrict__ pair_tok, float* __restrict__ pair_wt,
                       int* __restrict__ t2p){
  int t = blockIdx.x * blockDim.x + threadIdx.x;
  if(t >= NTOK) return;
  #pragma unroll
  for(int k = 0; k < 2; k++){
    int e = route_e[2*t + k];
    int pos = atomicAdd(&cursor[e], 1);
    int gidx = offsets[e] + pos;
    pair_tok[gidx] = t;
    pair_wt[gidx] = route_w[2*t + k];
    t2p[2*t + k] = gidx;                    // token -> its pair slots (for combine)
  }
}

// ---------------- stage A: h = silu(x@w1) * (x@w3), grouped by expert ----------------
// grid: (mtile<=64, ftile=32, expert=8); block 256 (4 waves, 2x2 over 128x128 tile)
// R3: double-buffered LDS, prefetch next K-step before compute, 1 barrier/step.
__global__ __launch_bounds__(256, 2) void k_ffn1(
    const unsigned short* __restrict__ xb,
    const unsigned short* __restrict__ w1t,   // [e][f][d] bf16
    const unsigned short* __restrict__ w3t,
    const int* __restrict__ counts, const int* __restrict__ offsets,
    const int* __restrict__ pair_tok,
    unsigned short* __restrict__ h)           // [pair][f] bf16
{
  int e = blockIdx.z;
  int cnt = counts[e];
  int m0 = blockIdx.x * 128;
  if(m0 >= cnt) return;
  int off = offsets[e];
  int n0 = blockIdx.y * 128;

  __shared__ short As[2][128*32];
  __shared__ short B1s[2][128*32];
  __shared__ short B3s[2][128*32];
  __shared__ int stok[128];

  int tid = threadIdx.x;
  if(tid < 128){
    int pr = m0 + tid;
    stok[tid] = pair_tok[off + imin(pr, cnt - 1)];  // clamp tail rows to a valid token
  }
  __syncthreads();

  int wave = tid >> 6, lane = tid & 63;
  int rr  = wave * 32 + (lane >> 2);        // row within 128-tile for staging instr 0
  // swizzled source granule within the row's 64B slice (see swizzle note above)
  int g16 = (((lane & 3) ^ ((lane >> 3) & 3))) * 16;
  int wo = wave * 32 * 32;                  // wave's 32-row LDS slice (shorts)

  const char* a0 = (const char*)xb + (size_t)stok[rr]      * (DMODEL*2) + g16;
  const char* a1 = (const char*)xb + (size_t)stok[rr + 16] * (DMODEL*2) + g16;
  const char* b1base = (const char*)w1t + ((size_t)e * FDIM + n0) * (DMODEL*2);
  const char* b3base = (const char*)w3t + ((size_t)e * FDIM + n0) * (DMODEL*2);
  const char* b1_0 = b1base + (size_t)rr * (DMODEL*2) + g16;
  const char* b1_1 = b1_0 + (size_t)16 * (DMODEL*2);
  const char* b3_0 = b3base + (size_t)rr * (DMODEL*2) + g16;
  const char* b3_1 = b3_0 + (size_t)16 * (DMODEL*2);

  f4v zero = {0.f, 0.f, 0.f, 0.f};
  f4v acc1[4][4], acc3[4][4];
  #pragma unroll
  for(int i = 0; i < 4; i++)
    #pragma unroll
    for(int j = 0; j < 4; j++){ acc1[i][j] = zero; acc3[i][j] = zero; }

  int wm = wave & 1, wn = wave >> 1;
  int lm = lane & 15, quad = lane >> 4;
  int rp = (quad ^ ((lm >> 1) & 3)) * 8;    // swizzled LDS position of granule `quad`

  // prologue: stage K-step 0 into buffer 0
  GLDS16(a0,   As[0]  + wo); GLDS16(a1,   As[0]  + wo + 512);
  GLDS16(b1_0, B1s[0] + wo); GLDS16(b1_1, B1s[0] + wo + 512);
  GLDS16(b3_0, B3s[0] + wo); GLDS16(b3_1, B3s[0] + wo + 512);
  __syncthreads();                          // vmcnt(0) drain + barrier: buf0 ready

  for(int kt = 0; kt < DMODEL; kt += 32){
    int c = (kt >> 5) & 1;
    if(kt + 32 < DMODEL){                   // prefetch next K-step into other buffer
      int kb = (kt + 32) * 2;
      short* an  = As[c^1]  + wo;
      short* b1n = B1s[c^1] + wo;
      short* b3n = B3s[c^1] + wo;
      GLDS16(a0   + kb, an);  GLDS16(a1   + kb, an  + 512);
      GLDS16(b1_0 + kb, b1n); GLDS16(b1_1 + kb, b1n + 512);
      GLDS16(b3_0 + kb, b3n); GLDS16(b3_1 + kb, b3n + 512);
    }

    const short* Ab  = As[c];
    const short* B1b = B1s[c];
    const short* B3b = B3s[c];
    s8v af[4], b1f[4], b3f[4];
    #pragma unroll
    for(int mi = 0; mi < 4; mi++)
      af[mi] = *(const s8v*)(Ab + (wm*64 + mi*16 + lm)*32 + rp);
    #pragma unroll
    for(int ni = 0; ni < 4; ni++){
      b1f[ni] = *(const s8v*)(B1b + (wn*64 + ni*16 + lm)*32 + rp);
      b3f[ni] = *(const s8v*)(B3b + (wn*64 + ni*16 + lm)*32 + rp);
    }
    #pragma unroll
    for(int mi = 0; mi < 4; mi++)
      #pragma unroll
      for(int ni = 0; ni < 4; ni++){
        acc1[mi][ni] = mfma16(af[mi], b1f[ni], acc1[mi][ni]);
        acc3[mi][ni] = mfma16(af[mi], b3f[ni], acc3[mi][ni]);
      }
    __syncthreads();   // vmcnt(0): prefetch landed; barrier: all reads of buf c done
  }

  // epilogue: SwiGLU, store bf16 h. C/D layout: col=lane&15, row=quad*4+reg
  #pragma unroll
  for(int mi = 0; mi < 4; mi++){
    int prb = m0 + wm*64 + mi*16 + quad*4;
    #pragma unroll
    for(int i = 0; i < 4; i++){
      int pr = prb + i;
      if(pr < cnt){
        size_t hrow = (size_t)(off + pr) * FDIM + n0 + wn*64 + lm;
        #pragma unroll
        for(int ni = 0; ni < 4; ni++){
          float p = acc1[mi][ni][i];
          float q = acc3[mi][ni][i];
          float hv = (p / (1.f + __expf(-p))) * q;   // silu(p)*q
          h[hrow + ni*16] = f2b(hv);
        }
      }
    }
  }
}

// ---------------- stage B: pout[pair] = wt * (h @ w2), grouped by expert ----------------
// grid: (mtile<=64, dtile=8, expert=8). Plain stores; combine kernel sums per token.
__global__ __launch_bounds__(256, 2) void k_ffn2(
    const unsigned short* __restrict__ h,     // [pair][f] bf16
    const unsigned short* __restrict__ w2t,   // [e][d][f] bf16
    const int* __restrict__ counts, const int* __restrict__ offsets,
    const float* __restrict__ pair_wt,
    float* __restrict__ pout)                 // [pair][d] fp32 (aliases w1t)
{
  int e = blockIdx.z;
  int cnt = counts[e];
  int m0 = blockIdx.x * 128;
  if(m0 >= cnt) return;
  int off = offsets[e];
  int n0 = blockIdx.y * 128;

  __shared__ short As[2][128*32];
  __shared__ short Bs[2][128*32];

  int tid = threadIdx.x, wave = tid >> 6, lane = tid & 63;
  int rr  = wave * 32 + (lane >> 2);
  int g16 = (((lane & 3) ^ ((lane >> 3) & 3))) * 16;   // swizzled source granule
  int wo = wave * 32 * 32;

  int pr0 = imin(m0 + rr,      cnt - 1);
  int pr1 = imin(m0 + rr + 16, cnt - 1);
  const char* a0 = (const char*)h + (size_t)(off + pr0) * (FDIM*2) + g16;
  const char* a1 = (const char*)h + (size_t)(off + pr1) * (FDIM*2) + g16;
  const char* bbase = (const char*)w2t + ((size_t)e * DMODEL + n0) * (FDIM*2);
  const char* b0 = bbase + (size_t)rr * (FDIM*2) + g16;
  const char* b1p = b0 + (size_t)16 * (FDIM*2);

  f4v zero = {0.f, 0.f, 0.f, 0.f};
  f4v acc[4][4];
  #pragma unroll
  for(int i = 0; i < 4; i++)
    #pragma unroll
    for(int j = 0; j < 4; j++) acc[i][j] = zero;

  int wm = wave & 1, wn = wave >> 1;
  int lm = lane & 15, quad = lane >> 4;
  int rp = (quad ^ ((lm >> 1) & 3)) * 8;    // swizzled LDS position of granule `quad`

  // prologue: stage K-step 0 into buffer 0
  GLDS16(a0, As[0] + wo); GLDS16(a1,  As[0] + wo + 512);
  GLDS16(b0, Bs[0] + wo); GLDS16(b1p, Bs[0] + wo + 512);
  __syncthreads();

  for(int kt = 0; kt < FDIM; kt += 32){
    int c = (kt >> 5) & 1;
    if(kt + 32 < FDIM){
      int kb = (kt + 32) * 2;
      short* an = As[c^1] + wo;
      short* bn = Bs[c^1] + wo;
      GLDS16(a0  + kb, an); GLDS16(a1  + kb, an + 512);
      GLDS16(b0  + kb, bn); GLDS16(b1p + kb, bn + 512);
    }

    const short* Ab = As[c];
    const short* Bb = Bs[c];
    s8v af[4], bf[4];
    #pragma unroll
    for(int mi = 0; mi < 4; mi++)
      af[mi] = *(const s8v*)(Ab + (wm*64 + mi*16 + lm)*32 + rp);
    #pragma unroll
    for(int ni = 0; ni < 4; ni++)
      bf[ni] = *(const s8v*)(Bb + (wn*64 + ni*16 + lm)*32 + rp);
    #pragma unroll
    for(int mi = 0; mi < 4; mi++)
      #pragma unroll
      for(int ni = 0; ni < 4; ni++)
        acc[mi][ni] = mfma16(af[mi], bf[ni], acc[mi][ni]);
    __syncthreads();
  }

  // epilogue: scale by gate weight, plain store to per-pair row
  #pragma unroll
  for(int mi = 0; mi < 4; mi++){
    int prb = m0 + wm*64 + mi*16 + quad*4;
    #pragma unroll
    for(int i = 0; i < 4; i++){
      int pr = prb + i;
      if(pr < cnt){
        int gp = off + pr;
        float wt = pair_wt[gp];
        float* prow = pout + (size_t)gp * DMODEL + n0 + wn*64 + lm;
        #pragma unroll
        for(int ni = 0; ni < 4; ni++)
          prow[ni*16] = acc[mi][ni][i] * wt;
      }
    }
  }
}

// ---------------- combine: out[t] = pout[p0(t)] + pout[p1(t)] ----------------
__global__ void k_combine(const float4* __restrict__ pout, const int* __restrict__ t2p,
                          float4* __restrict__ out){
  int t = blockIdx.x;
  int d = threadIdx.x;                       // 256 threads x float4 = 1024 floats
  int p0 = t2p[2*t], p1 = t2p[2*t + 1];
  out[(size_t)t * 256 + d] = pout[(size_t)p0 * 256 + d] + pout[(size_t)p1 * 256 + d];
}

extern "C" void kernel_launch(void* const* d_in, const int* in_sizes, int n_in,
                              void* d_out, int out_size, void* d_ws, size_t ws_size,
                              hipStream_t stream){
  const float* x  = (const float*)d_in[0];
  const float* gw = (const float*)d_in[1];
  const float* w1 = (const float*)d_in[2];
  const float* w3 = (const float*)d_in[3];
  const float* w2 = (const float*)d_in[4];
  float* out = (float*)d_out;

  char* ws = (char*)d_ws;
  size_t o = 0;
  auto alloc = [&](size_t b){ size_t r = o; o += (b + 255) & ~(size_t)255; return r; };
  unsigned short* xb  = (unsigned short*)(ws + alloc((size_t)NTOK * DMODEL * 2));
  unsigned short* w1t = (unsigned short*)(ws + alloc((size_t)NEXP * DMODEL * FDIM * 2));
  unsigned short* w3t = (unsigned short*)(ws + alloc((size_t)NEXP * DMODEL * FDIM * 2));
  unsigned short* w2t = (unsigned short*)(ws + alloc((size_t)NEXP * DMODEL * FDIM * 2));
  unsigned short* h   = (unsigned short*)(ws + alloc((size_t)2 * NTOK * FDIM * 2));
  int*   route_e  = (int*)  (ws + alloc(2 * NTOK * 4));
  float* route_w  = (float*)(ws + alloc(2 * NTOK * 4));
  int*   counts   = (int*)  (ws + alloc(256));
  int*   offsets  = (int*)  (ws + alloc(256));
  int*   cursor   = (int*)  (ws + alloc(256));
  int*   pair_tok = (int*)  (ws + alloc(2 * NTOK * 4));
  float* pair_wt  = (float*)(ws + alloc(2 * NTOK * 4));
  int*   t2p      = (int*)  (ws + alloc(2 * NTOK * 4));
  // pout [2*NTOK][DMODEL] fp32 = 64MB aliases w1t (64MB): w1t is dead after
  // k_ffn1 completes, pout is written by k_ffn2 afterward (same stream).
  float* pout = (float*)w1t;

  hipMemsetAsync(counts, 0, 256, stream);

  // bf16 conversions / weight transposes to [n][k] layout
  k_cvt<<<2048, 256, 0, stream>>>((const float4*)x, (ushort4*)xb, NTOK * DMODEL / 4);
  k_tr<<<dim3(FDIM/32, DMODEL/32, NEXP), 256, 0, stream>>>(w1, w1t, DMODEL, FDIM);
  k_tr<<<dim3(FDIM/32, DMODEL/32, NEXP), 256, 0, stream>>>(w3, w3t, DMODEL, FDIM);
  k_tr<<<dim3(DMODEL/32, FDIM/32, NEXP), 256, 0, stream>>>(w2, w2t, FDIM, DMODEL);

  // routing
  k_router<<<NTOK/4, 256, 0, stream>>>(x, gw, route_e, route_w, counts);
  k_scan<<<1, 64, 0, stream>>>(counts, offsets, cursor);
  k_fill<<<NTOK/256, 256, 0, stream>>>(route_e, route_w, offsets, cursor, pair_tok, pair_wt, t2p);

  // grouped GEMMs (worst-case grid; blocks past cnt exit early)
  k_ffn1<<<dim3(64, FDIM/128, NEXP), 256, 0, stream>>>(xb, w1t, w3t, counts, offsets, pair_tok, h);
  k_ffn2<<<dim3(64, DMODEL/128, NEXP), 256, 0, stream>>>(h, w2t, counts, offsets, pair_wt, pout);
  k_combine<<<NTOK, 256, 0, stream>>>((const float4*)pout, t2p, (float4*)out);
}

// Round 2
// 1360.972 us; speedup vs baseline: 1.1978x; 1.1978x over previous
//
#include <hip/hip_runtime.h>
#include <hip/hip_bf16.h>

// MoE FFN: B=4 T=2048 D=1024 F=4096 E=8 top-2, fp32 in/out.
// Strategy: fp32 router -> expert buckets -> bf16 MFMA grouped GEMMs
// (stage A: x@w1, x@w3 fused SwiGLU -> h; stage B: h@w2 -> pout -> combine).
// R2: XOR-swizzled LDS granule placement kills 4-8 way bank conflicts.
// R3: depth-1 dbuf + __syncthreads was a NO-OP (645us, MfmaUtil 18%) --
//     __syncthreads drains vmcnt(0), so the just-issued prefetch is exactly
//     what the barrier waits on. Known m99/m100 failure mode.
// R4: (a) T4 counted vmcnt: 3 LDS buffers, prefetch depth 2, raw s_barrier +
//     s_waitcnt vmcnt(N) lgkmcnt(0) where N = newest tile's loads (6 ffn1 /
//     4 ffn2) -- previous tile's loads certified, newest stay in flight.
//     (b) nontemporal h/pout stores: h's 134MB write stream was pushing the
//     LLC set to 295MB > 256MB -> weight re-fetch from HBM (FETCH 557MB vs
//     161MB unique). (c) XCD swizzle (nwg%8==0 -> bijective): consecutive
//     mtiles (same 512KB weight panel) on one XCD's L2.

#define NTOK 8192
#define DMODEL 1024
#define FDIM 4096
#define NEXP 8

typedef __attribute__((ext_vector_type(8))) short s8v;   // 8 x bf16 (4 VGPR)
typedef __attribute__((ext_vector_type(4))) float f4v;   // MFMA accumulator

__device__ __forceinline__ int imin(int a, int b){ return a < b ? a : b; }

// fp32 -> bf16 round-to-nearest-even
__device__ __forceinline__ unsigned short f2b(float f){
  union { float f; unsigned u; } v; v.f = f;
  unsigned r = v.u + 0x7fffu + ((v.u >> 16) & 1u);
  return (unsigned short)(r >> 16);
}

__device__ __forceinline__ f4v mfma16(s8v a, s8v b, f4v c){
  return __builtin_amdgcn_mfma_f32_16x16x32_bf16(a, b, c, 0, 0, 0);
}

// async global->LDS, 16B/lane; LDS dest = wave-uniform base + lane*16
#define GLDS16(gp, lp) __builtin_amdgcn_global_load_lds(                      \
    (const __attribute__((address_space(1))) void*)(gp),                      \
    (__attribute__((address_space(3))) void*)(lp), 16, 0, 0)

// LDS swizzle: source 16B-granule g of row r lives at LDS position g ^ ((r>>1)&3).
// Staging lane L (row r=L>>2, LDS pos L&3) therefore FETCHES source granule
// (L&3)^((L>>3)&3); fragment reads at row lm, granule quad use LDS position
// quad^((lm>>1)&3). Row-base offsets are multiples of 16 so they drop out.

// ---------------- fp32 -> bf16 elementwise (x) ----------------
__global__ void k_cvt(const float4* __restrict__ in, ushort4* __restrict__ out, int n4){
  int i = blockIdx.x * blockDim.x + threadIdx.x;
  int st = gridDim.x * blockDim.x;
  for(; i < n4; i += st){
    float4 v = in[i];
    ushort4 o;
    o.x = f2b(v.x); o.y = f2b(v.y); o.z = f2b(v.z); o.w = f2b(v.w);
    out[i] = o;
  }
}

// ---------------- fp32 [e][R][C] -> bf16 [e][C][R] transpose ----------------
__global__ void k_tr(const float* __restrict__ in, unsigned short* __restrict__ out,
                     int R, int C){
  __shared__ float tile[32][33];
  const float* src = in + (size_t)blockIdx.z * R * C;
  unsigned short* dst = out + (size_t)blockIdx.z * R * C;
  int bx = blockIdx.x * 32, by = blockIdx.y * 32;
  int tx = threadIdx.x & 31, ty = threadIdx.x >> 5;
  #pragma unroll
  for(int i = 0; i < 32; i += 8)
    tile[ty + i][tx] = src[(size_t)(by + ty + i) * C + bx + tx];
  __syncthreads();
  #pragma unroll
  for(int i = 0; i < 32; i += 8)
    dst[(size_t)(bx + ty + i) * R + by + tx] = f2b(tile[tx][ty + i]);
}

// ---------------- router: fp32 logits -> softmax -> top2 -> renorm ----------------
__global__ void k_router(const float* __restrict__ x, const float* __restrict__ gw,
                         int* __restrict__ route_e, float* __restrict__ route_w,
                         int* __restrict__ counts){
  int lane = threadIdx.x & 63;
  int t = blockIdx.x * 4 + (threadIdx.x >> 6);   // one wave per token
  const float* xr = x + (size_t)t * DMODEL;
  float acc[NEXP];
  #pragma unroll
  for(int e = 0; e < NEXP; e++) acc[e] = 0.f;
  for(int d = lane; d < DMODEL; d += 64){
    float xv = xr[d];
    const float* g = gw + d * NEXP;
    #pragma unroll
    for(int e = 0; e < NEXP; e++) acc[e] += xv * g[e];
  }
  #pragma unroll
  for(int off = 32; off > 0; off >>= 1){
    #pragma unroll
    for(int e = 0; e < NEXP; e++) acc[e] += __shfl_down(acc[e], off, 64);
  }
  if(lane == 0){
    float mx = acc[0];
    #pragma unroll
    for(int e = 1; e < NEXP; e++) mx = fmaxf(mx, acc[e]);
    float p[NEXP];
    #pragma unroll
    for(int e = 0; e < NEXP; e++) p[e] = expf(acc[e] - mx);
    int i0 = 0;
    #pragma unroll
    for(int e = 1; e < NEXP; e++) if(p[e] > p[i0]) i0 = e;     // first-max (jax tie rule)
    int i1 = (i0 == 0) ? 1 : 0;
    #pragma unroll
    for(int e = 0; e < NEXP; e++) if(e != i0 && p[e] > p[i1]) i1 = e;
    float inv = 1.f / (p[i0] + p[i1]);           // softmax denom cancels in ratio
    route_e[2*t]   = i0; route_e[2*t+1] = i1;
    route_w[2*t]   = p[i0] * inv;
    route_w[2*t+1] = p[i1] * inv;
    atomicAdd(&counts[i0], 1); atomicAdd(&counts[i1], 1);
  }
}

__global__ void k_scan(const int* __restrict__ counts, int* __restrict__ offsets,
                       int* __restrict__ cursor){
  if(threadIdx.x == 0){
    int o = 0;
    for(int e = 0; e < NEXP; e++){ offsets[e] = o; o += counts[e]; cursor[e] = 0; }
    offsets[NEXP] = o;
  }
}

__global__ void k_fill(const int* __restrict__ route_e, const float* __restrict__ route_w,
                       const int* __restrict__ offsets, int* __restrict__ cursor,
                       int* __restrict__ pair_tok, float* __restrict__ pair_wt,
                       int* __restrict__ t2p){
  int t = blockIdx.x * blockDim.x + threadIdx.x;
  if(t >= NTOK) return;
  #pragma unroll
  for(int k = 0; k < 2; k++){
    int e = route_e[2*t + k];
    int pos = atomicAdd(&cursor[e], 1);
    int gidx = offsets[e] + pos;
    pair_tok[gidx] = t;
    pair_wt[gidx] = route_w[2*t + k];
    t2p[2*t + k] = gidx;                    // token -> its pair slots (for combine)
  }
}

// ---------------- stage A: h = silu(x@w1) * (x@w3), grouped by expert ----------------
// grid: (mtile 64, ftile 32, expert 8); block 256 (4 waves, 2x2 over 128x128 tile)
// R4: 3-buffer LDS, prefetch depth 2, counted vmcnt across raw s_barrier.
__global__ __launch_bounds__(256, 2) void k_ffn1(
    const unsigned short* __restrict__ xb,
    const unsigned short* __restrict__ w1t,   // [e][f][d] bf16
    const unsigned short* __restrict__ w3t,
    const int* __restrict__ counts, const int* __restrict__ offsets,
    const int* __restrict__ pair_tok,
    unsigned short* __restrict__ h)           // [pair][f] bf16
{
  // XCD swizzle: nwg = 64*32*8 = 16384, chunk = 2048 (= one expert per XCD)
  unsigned lin = blockIdx.x + ((blockIdx.y + (blockIdx.z << 5)) << 6);
  unsigned swz = ((lin & 7u) << 11) | (lin >> 3);
  int e  = swz >> 11;
  int bx = swz & 63;
  int by = (swz >> 6) & 31;

  int cnt = counts[e];
  int m0 = bx * 128;
  if(m0 >= cnt) return;
  int off = offsets[e];
  int n0 = by * 128;

  __shared__ short As[3][128*32];
  __shared__ short B1s[3][128*32];
  __shared__ short B3s[3][128*32];
  __shared__ int stok[128];

  int tid = threadIdx.x;
  if(tid < 128){
    int pr = m0 + tid;
    stok[tid] = pair_tok[off + imin(pr, cnt - 1)];  // clamp tail rows to a valid token
  }
  __syncthreads();

  int wave = tid >> 6, lane = tid & 63;
  int rr  = wave * 32 + (lane >> 2);        // row within 128-tile for staging instr 0
  // swizzled source granule within the row's 64B slice (see swizzle note above)
  int g16 = (((lane & 3) ^ ((lane >> 3) & 3))) * 16;
  int wo = wave * 32 * 32;                  // wave's 32-row LDS slice (shorts)

  const char* a0 = (const char*)xb + (size_t)stok[rr]      * (DMODEL*2) + g16;
  const char* a1 = (const char*)xb + (size_t)stok[rr + 16] * (DMODEL*2) + g16;
  const char* b1base = (const char*)w1t + ((size_t)e * FDIM + n0) * (DMODEL*2);
  const char* b3base = (const char*)w3t + ((size_t)e * FDIM + n0) * (DMODEL*2);
  const char* b1_0 = b1base + (size_t)rr * (DMODEL*2) + g16;
  const char* b1_1 = b1_0 + (size_t)16 * (DMODEL*2);
  const char* b3_0 = b3base + (size_t)rr * (DMODEL*2) + g16;
  const char* b3_1 = b3_0 + (size_t)16 * (DMODEL*2);

  auto stage = [&](int tt, int buf){
    int kb = tt << 6;                       // 32 bf16 = 64 bytes per K-tile
    short* an  = &As[buf][wo];
    short* b1n = &B1s[buf][wo];
    short* b3n = &B3s[buf][wo];
    GLDS16(a0   + kb, an);  GLDS16(a1   + kb, an  + 512);
    GLDS16(b1_0 + kb, b1n); GLDS16(b1_1 + kb, b1n + 512);
    GLDS16(b3_0 + kb, b3n); GLDS16(b3_1 + kb, b3n + 512);
  };

  f4v zero = {0.f, 0.f, 0.f, 0.f};
  f4v acc1[4][4], acc3[4][4];
  #pragma unroll
  for(int i = 0; i < 4; i++)
    #pragma unroll
    for(int j = 0; j < 4; j++){ acc1[i][j] = zero; acc3[i][j] = zero; }

  int wm = wave & 1, wn = wave >> 1;
  int lm = lane & 15, quad = lane >> 4;
  int rp = (quad ^ ((lm >> 1) & 3)) * 8;    // swizzled LDS position of granule `quad`

  // prologue: tiles 0 and 1 in flight; certify tile 0 (allow tile 1's 6 loads)
  stage(0, 0); stage(1, 1);
  asm volatile("s_waitcnt vmcnt(6)" ::: "memory");
  __builtin_amdgcn_s_barrier();

  int bufc = 0;
  for(int t = 0; t < 32; ++t){
    int nb = t + 2;
    if(nb < 32){
      int bufn = bufc + 2; if(bufn >= 3) bufn -= 3;
      stage(nb, bufn);                      // depth-2 prefetch (WAR dist = 2 barriers)
    }

    const short* Ab  = As[bufc];
    const short* B1b = B1s[bufc];
    const short* B3b = B3s[bufc];
    s8v af[4], b1f[4], b3f[4];
    #pragma unroll
    for(int mi = 0; mi < 4; mi++)
      af[mi] = *(const s8v*)(Ab + (wm*64 + mi*16 + lm)*32 + rp);
    #pragma unroll
    for(int ni = 0; ni < 4; ni++){
      b1f[ni] = *(const s8v*)(B1b + (wn*64 + ni*16 + lm)*32 + rp);
      b3f[ni] = *(const s8v*)(B3b + (wn*64 + ni*16 + lm)*32 + rp);
    }
    #pragma unroll
    for(int mi = 0; mi < 4; mi++)
      #pragma unroll
      for(int ni = 0; ni < 4; ni++){
        acc1[mi][ni] = mfma16(af[mi], b1f[ni], acc1[mi][ni]);
        acc3[mi][ni] = mfma16(af[mi], b3f[ni], acc3[mi][ni]);
      }

    // counted wait: previous tile's 6 loads certified, newest 6 stay in flight.
    if(nb < 32)      asm volatile("s_waitcnt vmcnt(6) lgkmcnt(0)" ::: "memory");
    else if(t < 31)  asm volatile("s_waitcnt vmcnt(0) lgkmcnt(0)" ::: "memory");
    if(t < 31) __builtin_amdgcn_s_barrier();
    if(++bufc == 3) bufc = 0;
  }

  // epilogue: SwiGLU, store bf16 h (nontemporal: keep weights LLC-resident).
  // C/D layout: col=lane&15, row=quad*4+reg
  #pragma unroll
  for(int mi = 0; mi < 4; mi++){
    int prb = m0 + wm*64 + mi*16 + quad*4;
    #pragma unroll
    for(int i = 0; i < 4; i++){
      int pr = prb + i;
      if(pr < cnt){
        size_t hrow = (size_t)(off + pr) * FDIM + n0 + wn*64 + lm;
        #pragma unroll
        for(int ni = 0; ni < 4; ni++){
          float p = acc1[mi][ni][i];
          float q = acc3[mi][ni][i];
          float hv = (p / (1.f + __expf(-p))) * q;   // silu(p)*q
          __builtin_nontemporal_store((unsigned short)f2b(hv), &h[hrow + ni*16]);
        }
      }
    }
  }
}

// ---------------- stage B: pout[pair] = wt * (h @ w2), grouped by expert ----------------
// grid: (mtile 64, dtile 8, expert 8). Plain stores; combine kernel sums per token.
__global__ __launch_bounds__(256, 2) void k_ffn2(
    const unsigned short* __restrict__ h,     // [pair][f] bf16
    const unsigned short* __restrict__ w2t,   // [e][d][f] bf16
    const int* __restrict__ counts, const int* __restrict__ offsets,
    const float* __restrict__ pair_wt,
    float* __restrict__ pout)                 // [pair][d] fp32 (aliases w1t)
{
  // XCD swizzle: nwg = 64*8*8 = 4096, chunk = 512 (= one expert per XCD)
  unsigned lin = blockIdx.x + ((blockIdx.y + (blockIdx.z << 3)) << 6);
  unsigned swz = ((lin & 7u) << 9) | (lin >> 3);
  int e  = swz >> 9;
  int bx = swz & 63;
  int by = (swz >> 6) & 7;

  int cnt = counts[e];
  int m0 = bx * 128;
  if(m0 >= cnt) return;
  int off = offsets[e];
  int n0 = by * 128;

  __shared__ short As[3][128*32];
  __shared__ short Bs[3][128*32];

  int tid = threadIdx.x, wave = tid >> 6, lane = tid & 63;
  int rr  = wave * 32 + (lane >> 2);
  int g16 = (((lane & 3) ^ ((lane >> 3) & 3))) * 16;   // swizzled source granule
  int wo = wave * 32 * 32;

  int pr0 = imin(m0 + rr,      cnt - 1);
  int pr1 = imin(m0 + rr + 16, cnt - 1);
  const char* a0 = (const char*)h + (size_t)(off + pr0) * (FDIM*2) + g16;
  const char* a1 = (const char*)h + (size_t)(off + pr1) * (FDIM*2) + g16;
  const char* bbase = (const char*)w2t + ((size_t)e * DMODEL + n0) * (FDIM*2);
  const char* b0 = bbase + (size_t)rr * (FDIM*2) + g16;
  const char* b1p = b0 + (size_t)16 * (FDIM*2);

  auto stage = [&](int tt, int buf){
    int kb = tt << 6;
    short* an = &As[buf][wo];
    short* bn = &Bs[buf][wo];
    GLDS16(a0 + kb, an); GLDS16(a1  + kb, an + 512);
    GLDS16(b0 + kb, bn); GLDS16(b1p + kb, bn + 512);
  };

  f4v zero = {0.f, 0.f, 0.f, 0.f};
  f4v acc[4][4];
  #pragma unroll
  for(int i = 0; i < 4; i++)
    #pragma unroll
    for(int j = 0; j < 4; j++) acc[i][j] = zero;

  int wm = wave & 1, wn = wave >> 1;
  int lm = lane & 15, quad = lane >> 4;
  int rp = (quad ^ ((lm >> 1) & 3)) * 8;    // swizzled LDS position of granule `quad`

  // prologue: tiles 0 and 1 in flight; certify tile 0 (allow tile 1's 4 loads)
  stage(0, 0); stage(1, 1);
  asm volatile("s_waitcnt vmcnt(4)" ::: "memory");
  __builtin_amdgcn_s_barrier();

  int bufc = 0;
  for(int t = 0; t < 128; ++t){
    int nb = t + 2;
    if(nb < 128){
      int bufn = bufc + 2; if(bufn >= 3) bufn -= 3;
      stage(nb, bufn);
    }

    const short* Ab = As[bufc];
    const short* Bb = Bs[bufc];
    s8v af[4], bf[4];
    #pragma unroll
    for(int mi = 0; mi < 4; mi++)
      af[mi] = *(const s8v*)(Ab + (wm*64 + mi*16 + lm)*32 + rp);
    #pragma unroll
    for(int ni = 0; ni < 4; ni++)
      bf[ni] = *(const s8v*)(Bb + (wn*64 + ni*16 + lm)*32 + rp);
    #pragma unroll
    for(int mi = 0; mi < 4; mi++)
      #pragma unroll
      for(int ni = 0; ni < 4; ni++)
        acc[mi][ni] = mfma16(af[mi], bf[ni], acc[mi][ni]);

    if(nb < 128)      asm volatile("s_waitcnt vmcnt(4) lgkmcnt(0)" ::: "memory");
    else if(t < 127)  asm volatile("s_waitcnt vmcnt(0) lgkmcnt(0)" ::: "memory");
    if(t < 127) __builtin_amdgcn_s_barrier();
    if(++bufc == 3) bufc = 0;
  }

  // epilogue: scale by gate weight, nontemporal store to per-pair row
  #pragma unroll
  for(int mi = 0; mi < 4; mi++){
    int prb = m0 + wm*64 + mi*16 + quad*4;
    #pragma unroll
    for(int i = 0; i < 4; i++){
      int pr = prb + i;
      if(pr < cnt){
        int gp = off + pr;
        float wt = pair_wt[gp];
        float* prow = pout + (size_t)gp * DMODEL + n0 + wn*64 + lm;
        #pragma unroll
        for(int ni = 0; ni < 4; ni++)
          __builtin_nontemporal_store(acc[mi][ni][i] * wt, prow + ni*16);
      }
    }
  }
}

// ---------------- combine: out[t] = pout[p0(t)] + pout[p1(t)] ----------------
__global__ void k_combine(const float4* __restrict__ pout, const int* __restrict__ t2p,
                          float4* __restrict__ out){
  int t = blockIdx.x;
  int d = threadIdx.x;                       // 256 threads x float4 = 1024 floats
  int p0 = t2p[2*t], p1 = t2p[2*t + 1];
  out[(size_t)t * 256 + d] = pout[(size_t)p0 * 256 + d] + pout[(size_t)p1 * 256 + d];
}

extern "C" void kernel_launch(void* const* d_in, const int* in_sizes, int n_in,
                              void* d_out, int out_size, void* d_ws, size_t ws_size,
                              hipStream_t stream){
  const float* x  = (const float*)d_in[0];
  const float* gw = (const float*)d_in[1];
  const float* w1 = (const float*)d_in[2];
  const float* w3 = (const float*)d_in[3];
  const float* w2 = (const float*)d_in[4];
  float* out = (float*)d_out;

  char* ws = (char*)d_ws;
  size_t o = 0;
  auto alloc = [&](size_t b){ size_t r = o; o += (b + 255) & ~(size_t)255; return r; };
  unsigned short* xb  = (unsigned short*)(ws + alloc((size_t)NTOK * DMODEL * 2));
  unsigned short* w1t = (unsigned short*)(ws + alloc((size_t)NEXP * DMODEL * FDIM * 2));
  unsigned short* w3t = (unsigned short*)(ws + alloc((size_t)NEXP * DMODEL * FDIM * 2));
  unsigned short* w2t = (unsigned short*)(ws + alloc((size_t)NEXP * DMODEL * FDIM * 2));
  unsigned short* h   = (unsigned short*)(ws + alloc((size_t)2 * NTOK * FDIM * 2));
  int*   route_e  = (int*)  (ws + alloc(2 * NTOK * 4));
  float* route_w  = (float*)(ws + alloc(2 * NTOK * 4));
  int*   counts   = (int*)  (ws + alloc(256));
  int*   offsets  = (int*)  (ws + alloc(256));
  int*   cursor   = (int*)  (ws + alloc(256));
  int*   pair_tok = (int*)  (ws + alloc(2 * NTOK * 4));
  float* pair_wt  = (float*)(ws + alloc(2 * NTOK * 4));
  int*   t2p      = (int*)  (ws + alloc(2 * NTOK * 4));
  // pout [2*NTOK][DMODEL] fp32 = 64MB aliases w1t (64MB): w1t is dead after
  // k_ffn1 completes, pout is written by k_ffn2 afterward (same stream).
  float* pout = (float*)w1t;

  hipMemsetAsync(counts, 0, 256, stream);

  // bf16 conversions / weight transposes to [n][k] layout
  k_cvt<<<2048, 256, 0, stream>>>((const float4*)x, (ushort4*)xb, NTOK * DMODEL / 4);
  k_tr<<<dim3(FDIM/32, DMODEL/32, NEXP), 256, 0, stream>>>(w1, w1t, DMODEL, FDIM);
  k_tr<<<dim3(FDIM/32, DMODEL/32, NEXP), 256, 0, stream>>>(w3, w3t, DMODEL, FDIM);
  k_tr<<<dim3(DMODEL/32, FDIM/32, NEXP), 256, 0, stream>>>(w2, w2t, FDIM, DMODEL);

  // routing
  k_router<<<NTOK/4, 256, 0, stream>>>(x, gw, route_e, route_w, counts);
  k_scan<<<1, 64, 0, stream>>>(counts, offsets, cursor);
  k_fill<<<NTOK/256, 256, 0, stream>>>(route_e, route_w, offsets, cursor, pair_tok, pair_wt, t2p);

  // grouped GEMMs (worst-case grid; blocks past cnt exit early)
  k_ffn1<<<dim3(64, FDIM/128, NEXP), 256, 0, stream>>>(xb, w1t, w3t, counts, offsets, pair_tok, h);
  k_ffn2<<<dim3(64, DMODEL/128, NEXP), 256, 0, stream>>>(h, w2t, counts, offsets, pair_wt, pout);
  k_combine<<<NTOK, 256, 0, stream>>>((const float4*)pout, t2p, (float4*)out);
}